// Round 15
// baseline (378.784 us; speedup 1.0000x reference)
//
#include <hip/hip_runtime.h>
#include <math.h>

constexpr int Nn = 16384;
constexpr size_t NS = (size_t)Nn * 16;      // dwords per channel plane of npts
constexpr int GPW = 4;                      // 4-pt groups per wave; 16 pts/wave; 64/block

// ---- DPP helpers (rows of 16, pure VALU) ----
template <int CTRL>
__device__ __forceinline__ float dpp_f(float x) {
    return __int_as_float(
        __builtin_amdgcn_update_dpp(0, __float_as_int(x), CTRL, 0xF, 0xF, false));
}
__device__ __forceinline__ float rsum16(float v) {
    v += dpp_f<0x128>(v); v += dpp_f<0x124>(v);
    v += dpp_f<0x122>(v); v += dpp_f<0x121>(v);
    return v;
}
__device__ __forceinline__ float rmax16(float v) {
    v = fmaxf(v, dpp_f<0x128>(v)); v = fmaxf(v, dpp_f<0x124>(v));
    v = fmaxf(v, dpp_f<0x122>(v)); v = fmaxf(v, dpp_f<0x121>(v));
    return v;
}

// LDS-visibility barrier (no vmcnt drain): prefetched global loads stay in flight.
#define BAR() do { asm volatile("s_waitcnt lgkmcnt(0)" ::: "memory"); \
    __builtin_amdgcn_s_barrier(); asm volatile("" ::: "memory"); } while (0)

// ====== Fused, barrier-free-loop kernel (R14 structure, spill-safe reg cap) ======
// Block = 4 waves = 64 points. Phase Q computes qk/pp for the block's 64 points
// into qk_lds; ONE barrier; then each wave independently streams its 16 points
// (4 groups of 4) across ALL 64 channels: lane = (nn,s), logit -> DPP softmax ->
// fused vbar+Wv matvec with per-element liveness prefetch. No in-loop barriers.
// __launch_bounds__(256,3): VGPR cap ~170 — peak liveness ~130 fits (R14's
// (256,4) cap=128 caused the npv[] scratch spill: WRITE 297MB, VGPR 64).
__global__ __launch_bounds__(256, 3) void attn_fused_kernel(
    const float* __restrict__ xyz, const float* __restrict__ nxyz,
    const float* __restrict__ points, const float* __restrict__ npts,
    const float* __restrict__ Wk, const float* __restrict__ Wv,
    const float* __restrict__ Wp, float* __restrict__ out)
{
    __shared__ float wvT[67 * 68];              // [c][o], stride 68
    __shared__ float qk_lds[64 * 68];           // [pt_local][64 qk + 4 pp]

    const int tid = threadIdx.x;
    const int w = tid >> 6;
    const int l = tid & 63;
    const int s = l & 15;
    const int nn = l >> 4;
    const int gptbase = blockIdx.x * 64;        // 64-pt chunk, never straddles b
    const int b = gptbase >> 14;
    const int ngbase = gptbase & (Nn - 1);
    const int nw = ngbase + w * 16;             // this wave's first point col

    // ---- one-time Wv transpose stage ----
    for (int idx = tid; idx < 64 * 67; idx += 256) {
        const int o = idx / 67, c = idx - o * 67;
        wvT[c * 68 + o] = Wv[idx];
    }

    // ---- group-0 prefetch FIRST: hides under phase Q ----
    const float* npb0 = npts + (size_t)(b * 64) * NS + (size_t)nw * 16 + l;  // +c*NS +g*64
    float npv[64];
#pragma unroll
    for (int c = 0; c < 64; ++c) npv[c] = npb0[(size_t)c * NS];
    float nxa = nxyz[((size_t)(b * 3 + 0) * Nn + nw) * 16 + l];
    float nxb = nxyz[((size_t)(b * 3 + 1) * Nn + nw) * 16 + l];
    float nxc = nxyz[((size_t)(b * 3 + 2) * Nn + nw) * 16 + l];
    float xa = xyz[(size_t)(b * 3 + 0) * Nn + nw + nn];
    float xb = xyz[(size_t)(b * 3 + 1) * Nn + nw + nn];
    float xc = xyz[(size_t)(b * 3 + 2) * Nn + nw + nn];

    // ---- phase Q: qk = Wk^T (q*scale), pp = Wp^T qk for all 64 block points ----
    // thread = (pt_local = w*16 + (l&15), quarter = l>>4)
    {
        const int quarter = l >> 4;
        const int ptl = w * 16 + (l & 15);
        const int n = ngbase + ptl;

        float qk[16];
#pragma unroll
        for (int k = 0; k < 16; ++k) qk[k] = 0.f;

        const float* prow = points + (size_t)b * 64 * Nn + n;
        const float* wkq = Wk + 16 * quarter;
#pragma unroll 4
        for (int c = 0; c < 64; ++c) {
            const float qv = prow[(size_t)c * Nn];
            const float4 w0 = *(const float4*)(wkq + c * 64 + 0);
            const float4 w1 = *(const float4*)(wkq + c * 64 + 4);
            const float4 w2 = *(const float4*)(wkq + c * 64 + 8);
            const float4 w3 = *(const float4*)(wkq + c * 64 + 12);
            qk[0]  = fmaf(qv, w0.x, qk[0]);  qk[1]  = fmaf(qv, w0.y, qk[1]);
            qk[2]  = fmaf(qv, w0.z, qk[2]);  qk[3]  = fmaf(qv, w0.w, qk[3]);
            qk[4]  = fmaf(qv, w1.x, qk[4]);  qk[5]  = fmaf(qv, w1.y, qk[5]);
            qk[6]  = fmaf(qv, w1.z, qk[6]);  qk[7]  = fmaf(qv, w1.w, qk[7]);
            qk[8]  = fmaf(qv, w2.x, qk[8]);  qk[9]  = fmaf(qv, w2.y, qk[9]);
            qk[10] = fmaf(qv, w2.z, qk[10]); qk[11] = fmaf(qv, w2.w, qk[11]);
            qk[12] = fmaf(qv, w3.x, qk[12]); qk[13] = fmaf(qv, w3.y, qk[13]);
            qk[14] = fmaf(qv, w3.z, qk[14]); qk[15] = fmaf(qv, w3.w, qk[15]);
        }
#pragma unroll
        for (int k = 0; k < 16; ++k) qk[k] *= 0.125f;   // fold SCALE

        float p0 = 0.f, p1 = 0.f, p2 = 0.f, p3 = 0.f;
#pragma unroll
        for (int k = 0; k < 16; ++k) {
            const float4 wp4 = *(const float4*)(Wp + (16 * quarter + k) * 4);
            p0 = fmaf(qk[k], wp4.x, p0);
            p1 = fmaf(qk[k], wp4.y, p1);
            p2 = fmaf(qk[k], wp4.z, p2);
            p3 = fmaf(qk[k], wp4.w, p3);
        }
        p0 += __shfl_xor(p0, 16); p0 += __shfl_xor(p0, 32);
        p1 += __shfl_xor(p1, 16); p1 += __shfl_xor(p1, 32);
        p2 += __shfl_xor(p2, 16); p2 += __shfl_xor(p2, 32);
        p3 += __shfl_xor(p3, 16); p3 += __shfl_xor(p3, 32);

        float* orow = qk_lds + ptl * 68 + 16 * quarter;
        ((float4*)orow)[0] = make_float4(qk[0],  qk[1],  qk[2],  qk[3]);
        ((float4*)orow)[1] = make_float4(qk[4],  qk[5],  qk[6],  qk[7]);
        ((float4*)orow)[2] = make_float4(qk[8],  qk[9],  qk[10], qk[11]);
        ((float4*)orow)[3] = make_float4(qk[12], qk[13], qk[14], qk[15]);
        if (quarter == 0)
            *(float4*)(qk_lds + ptl * 68 + 64) = make_float4(p0, p1, p2, p3);
    }
    BAR();   // qk_lds + wvT visible; group-0 global prefetch still in flight

    // ---- main loop: fully wave-independent, zero barriers ----
#pragma unroll 1
    for (int g = 0; g < GPW; ++g) {
        const int ng = nw + 4 * g;

        // relative position for this lane's (nn, s); nx dies here
        const float d0 = xa - nxa, d1 = xb - nxb, d2 = xc - nxc;
        const float dn = sqrtf(d0 * d0 + d1 * d1 + d2 * d2);

        // prefetch next group's nx/xx immediately (longest use distance);
        // clamp on last group -> redundant cached reload, keeps code uniform
        {
            const int gn = (g + 1 < GPW) ? g + 1 : g;
            const size_t go = (size_t)gn * 64;
            nxa = nxyz[((size_t)(b * 3 + 0) * Nn + nw) * 16 + go + l];
            nxb = nxyz[((size_t)(b * 3 + 1) * Nn + nw) * 16 + go + l];
            nxc = nxyz[((size_t)(b * 3 + 2) * Nn + nw) * 16 + go + l];
            xa = xyz[(size_t)(b * 3 + 0) * Nn + nw + 4 * gn + nn];
            xb = xyz[(size_t)(b * 3 + 1) * Nn + nw + 4 * gn + nn];
            xc = xyz[(size_t)(b * 3 + 2) * Nn + nw + 4 * gn + nn];
        }

        // ---- logit = qk . np + pp . pos  (qk: LDS b128 broadcast, 4 rows/instr) ----
        const float* qrow = qk_lds + (w * 16 + 4 * g + nn) * 68;
        float l0 = 0.f, l1 = 0.f, l2 = 0.f, l3 = 0.f;
#pragma unroll
        for (int j = 0; j < 16; ++j) {
            const float4 qv = ((const float4*)qrow)[j];
            l0 = fmaf(qv.x, npv[4 * j + 0], l0);
            l1 = fmaf(qv.y, npv[4 * j + 1], l1);
            l2 = fmaf(qv.z, npv[4 * j + 2], l2);
            l3 = fmaf(qv.w, npv[4 * j + 3], l3);
        }
        const float4 pp = ((const float4*)qrow)[16];
        float logit = (l0 + l1) + (l2 + l3);
        logit += pp.x * d0 + pp.y * d1 + pp.z * d2 + pp.w * dn;
        // (bp term constant in s -> cancels in softmax)

        // ---- softmax over s (pure DPP in rows of 16) ----
        const float mx = rmax16(logit);
        const float e = __expf(logit - mx);
        const float se = rsum16(e);
        const float attn = e / se;

        // ---- fused vbar + Wv matvec; npv[c] prefetched in-place after last use ----
        const float* npb_n = npb0 + (size_t)((g + 1 < GPW) ? g + 1 : g) * 64;
        float4 oa = make_float4(0.f, 0.f, 0.f, 0.f);
#pragma unroll
        for (int c = 0; c < 64; ++c) {
            const float r = rsum16(attn * npv[c]);              // vbar[c, nn]
            const float4 wq = *(const float4*)&wvT[c * 68 + 4 * s];
            oa.x = fmaf(r, wq.x, oa.x);
            oa.y = fmaf(r, wq.y, oa.y);
            oa.z = fmaf(r, wq.z, oa.z);
            oa.w = fmaf(r, wq.w, oa.w);
            npv[c] = npb_n[(size_t)c * NS];                     // liveness prefetch
        }
        {   // tail channels 64..66 (= tmp d0,d1,d2); d dies here
            const float t0 = rsum16(attn * d0);
            const float t1 = rsum16(attn * d1);
            const float t2 = rsum16(attn * d2);
            const float4 wA = *(const float4*)&wvT[64 * 68 + 4 * s];
            const float4 wB = *(const float4*)&wvT[65 * 68 + 4 * s];
            const float4 wC = *(const float4*)&wvT[66 * 68 + 4 * s];
            oa.x += t0 * wA.x + t1 * wB.x + t2 * wC.x;
            oa.y += t0 * wA.y + t1 * wB.y + t2 * wC.y;
            oa.z += t0 * wA.z + t1 * wB.z + t2 * wC.z;
            oa.w += t0 * wA.w + t1 * wB.w + t2 * wC.w;
        }

        // stores: out[o = 4s+j][ng+nn] — 16 x 16B segments per instr
        float* ob = out + ((size_t)(b * 64 + 4 * s)) * Nn + ng + nn;
        ob[0]              = oa.x;
        ob[(size_t)Nn]     = oa.y;
        ob[(size_t)Nn * 2] = oa.z;
        ob[(size_t)Nn * 3] = oa.w;
    }
}

extern "C" void kernel_launch(void* const* d_in, const int* in_sizes, int n_in,
                              void* d_out, int out_size, void* d_ws, size_t ws_size,
                              hipStream_t stream) {
    const float* xyz    = (const float*)d_in[0];
    const float* nxyz   = (const float*)d_in[1];
    const float* points = (const float*)d_in[2];
    const float* npts   = (const float*)d_in[3];
    const float* Wk     = (const float*)d_in[4];
    const float* Wv     = (const float*)d_in[5];
    const float* Wp     = (const float*)d_in[6];
    // d_in[7] = bp — unused: constant-in-s logit shift cancels in softmax
    float* out = (float*)d_out;

    hipLaunchKernelGGL(attn_fused_kernel, dim3(1024), dim3(256), 0, stream,
                       xyz, nxyz, points, npts, Wk, Wv, Wp, out);
}

// Round 16
// 292.182 us; speedup vs baseline: 1.2964x; 1.2964x over previous
//
#include <hip/hip_runtime.h>
#include <math.h>

constexpr int Nn = 16384;
constexpr size_t NS = (size_t)Nn * 16;      // dwords per channel plane of npts
constexpr int ITERS = 8;                    // 2 pts/iter/wave -> 16 pts/wave, 64/block

// ---- DPP helpers (rows of 16, pure VALU) ----
template <int CTRL>
__device__ __forceinline__ float dpp_f(float x) {
    return __int_as_float(
        __builtin_amdgcn_update_dpp(0, __float_as_int(x), CTRL, 0xF, 0xF, false));
}
__device__ __forceinline__ float rsum16(float v) {
    v += dpp_f<0x128>(v); v += dpp_f<0x124>(v);
    v += dpp_f<0x122>(v); v += dpp_f<0x121>(v);
    return v;
}
__device__ __forceinline__ float rmax16(float v) {
    v = fmaxf(v, dpp_f<0x128>(v)); v = fmaxf(v, dpp_f<0x124>(v));
    v = fmaxf(v, dpp_f<0x122>(v)); v = fmaxf(v, dpp_f<0x121>(v));
    return v;
}

// LDS-visibility barrier (no vmcnt drain)
#define BAR() do { asm volatile("s_waitcnt lgkmcnt(0)" ::: "memory"); \
    __builtin_amdgcn_s_barrier(); asm volatile("" ::: "memory"); } while (0)

// ====== Fused kernel, barrier-free loop, 32-float streaming state ======
// Block = 4 waves = 64 points. Phase Q -> qk_lds (one barrier). Main loop:
// wave independently processes 2 points/iter; lane = (h = l>>5, nn = (l>>4)&1,
// s = l&15) holds channels 32h..32h+31 of point nn. Cross-half combines are
// single in-wave __shfl_xor(...,32); pos/pp/tail live on h=1 lanes only.
__global__ __launch_bounds__(256, 4) void attn_fused_kernel(
    const float* __restrict__ xyz, const float* __restrict__ nxyz,
    const float* __restrict__ points, const float* __restrict__ npts,
    const float* __restrict__ Wk, const float* __restrict__ Wv,
    const float* __restrict__ Wp, float* __restrict__ out)
{
    __shared__ float wvT[67 * 68];              // [c][o], stride 68
    __shared__ float qk_lds[64 * 68];           // [pt_local][64 qk + 4 pp]

    const int tid = threadIdx.x;
    const int w = tid >> 6;
    const int l = tid & 63;
    const int s = l & 15;
    const int nn = (l >> 4) & 1;
    const int h = l >> 5;                       // channel half
    const int gptbase = blockIdx.x * 64;        // 64-pt chunk, never straddles b
    const int b = gptbase >> 14;
    const int ngbase = gptbase & (Nn - 1);
    const int nw = ngbase + w * 16;             // this wave's first point col

    // ---- one-time Wv transpose stage ----
    for (int idx = tid; idx < 64 * 67; idx += 256) {
        const int o = idx / 67, c = idx - o * 67;
        wvT[c * 68 + o] = Wv[idx];
    }

    // ---- phase Q: qk = Wk^T (q*scale), pp = Wp^T qk for all 64 block points ----
    // thread = (pt_local = w*16 + (l&15), quarter = l>>4)
    {
        const int quarter = l >> 4;
        const int ptl = w * 16 + (l & 15);
        const int n = ngbase + ptl;

        float qk[16];
#pragma unroll
        for (int k = 0; k < 16; ++k) qk[k] = 0.f;

        const float* prow = points + (size_t)b * 64 * Nn + n;
        const float* wkq = Wk + 16 * quarter;
#pragma unroll 4
        for (int c = 0; c < 64; ++c) {
            const float qv = prow[(size_t)c * Nn];
            const float4 w0 = *(const float4*)(wkq + c * 64 + 0);
            const float4 w1 = *(const float4*)(wkq + c * 64 + 4);
            const float4 w2 = *(const float4*)(wkq + c * 64 + 8);
            const float4 w3 = *(const float4*)(wkq + c * 64 + 12);
            qk[0]  = fmaf(qv, w0.x, qk[0]);  qk[1]  = fmaf(qv, w0.y, qk[1]);
            qk[2]  = fmaf(qv, w0.z, qk[2]);  qk[3]  = fmaf(qv, w0.w, qk[3]);
            qk[4]  = fmaf(qv, w1.x, qk[4]);  qk[5]  = fmaf(qv, w1.y, qk[5]);
            qk[6]  = fmaf(qv, w1.z, qk[6]);  qk[7]  = fmaf(qv, w1.w, qk[7]);
            qk[8]  = fmaf(qv, w2.x, qk[8]);  qk[9]  = fmaf(qv, w2.y, qk[9]);
            qk[10] = fmaf(qv, w2.z, qk[10]); qk[11] = fmaf(qv, w2.w, qk[11]);
            qk[12] = fmaf(qv, w3.x, qk[12]); qk[13] = fmaf(qv, w3.y, qk[13]);
            qk[14] = fmaf(qv, w3.z, qk[14]); qk[15] = fmaf(qv, w3.w, qk[15]);
        }
#pragma unroll
        for (int k = 0; k < 16; ++k) qk[k] *= 0.125f;   // fold SCALE

        float p0 = 0.f, p1 = 0.f, p2 = 0.f, p3 = 0.f;
#pragma unroll
        for (int k = 0; k < 16; ++k) {
            const float4 wp4 = *(const float4*)(Wp + (16 * quarter + k) * 4);
            p0 = fmaf(qk[k], wp4.x, p0);
            p1 = fmaf(qk[k], wp4.y, p1);
            p2 = fmaf(qk[k], wp4.z, p2);
            p3 = fmaf(qk[k], wp4.w, p3);
        }
        p0 += __shfl_xor(p0, 16); p0 += __shfl_xor(p0, 32);
        p1 += __shfl_xor(p1, 16); p1 += __shfl_xor(p1, 32);
        p2 += __shfl_xor(p2, 16); p2 += __shfl_xor(p2, 32);
        p3 += __shfl_xor(p3, 16); p3 += __shfl_xor(p3, 32);

        float* orow = qk_lds + ptl * 68 + 16 * quarter;
        ((float4*)orow)[0] = make_float4(qk[0],  qk[1],  qk[2],  qk[3]);
        ((float4*)orow)[1] = make_float4(qk[4],  qk[5],  qk[6],  qk[7]);
        ((float4*)orow)[2] = make_float4(qk[8],  qk[9],  qk[10], qk[11]);
        ((float4*)orow)[3] = make_float4(qk[12], qk[13], qk[14], qk[15]);
        if (quarter == 0)
            *(float4*)(qk_lds + ptl * 68 + 64) = make_float4(p0, p1, p2, p3);
    }
    BAR();   // qk_lds + wvT visible (single barrier in the kernel)

    // ---- streaming state: 32 floats/lane + pos scalars (h=1 only) ----
    // np address: plane (32h+c), column (pt)*16 + s
    const float* npb0 = npts + (size_t)(b * 64 + 32 * h) * NS
                        + (size_t)nw * 16 + (l & 31);      // + c*NS + iter*32
    float npv[32];
#pragma unroll
    for (int c = 0; c < 32; ++c) npv[c] = npb0[(size_t)c * NS];

    float nxa = 0.f, nxb = 0.f, nxc = 0.f, xa = 0.f, xb = 0.f, xc = 0.f;
    if (h) {    // h=1 lanes own pos: 32 dwords = pts {nw, nw+1} x 16 s
        nxa = nxyz[((size_t)(b * 3 + 0) * Nn + nw) * 16 + (l & 31)];
        nxb = nxyz[((size_t)(b * 3 + 1) * Nn + nw) * 16 + (l & 31)];
        nxc = nxyz[((size_t)(b * 3 + 2) * Nn + nw) * 16 + (l & 31)];
        xa = xyz[(size_t)(b * 3 + 0) * Nn + nw + nn];
        xb = xyz[(size_t)(b * 3 + 1) * Nn + nw + nn];
        xc = xyz[(size_t)(b * 3 + 2) * Nn + nw + nn];
    }

#pragma unroll 1
    for (int t = 0; t < ITERS; ++t) {
        const int ng = nw + 2 * t;

        // relative position (h=1 lanes); dn for logit, d for tail
        float d0 = 0.f, d1 = 0.f, d2 = 0.f, dn = 0.f;
        float4 pp = make_float4(0.f, 0.f, 0.f, 0.f);
        if (h) {
            d0 = xa - nxa; d1 = xb - nxb; d2 = xc - nxc;
            dn = sqrtf(d0 * d0 + d1 * d1 + d2 * d2);
            pp = *(const float4*)(qk_lds + (w * 16 + 2 * t + nn) * 68 + 64);
            // prefetch next iter's pos immediately (clamped on last iter)
            const int tn = (t + 1 < ITERS) ? t + 1 : t;
            nxa = nxyz[((size_t)(b * 3 + 0) * Nn + nw + 2 * tn) * 16 + (l & 31)];
            nxb = nxyz[((size_t)(b * 3 + 1) * Nn + nw + 2 * tn) * 16 + (l & 31)];
            nxc = nxyz[((size_t)(b * 3 + 2) * Nn + nw + 2 * tn) * 16 + (l & 31)];
            xa = xyz[(size_t)(b * 3 + 0) * Nn + nw + 2 * tn + nn];
            xb = xyz[(size_t)(b * 3 + 1) * Nn + nw + 2 * tn + nn];
            xc = xyz[(size_t)(b * 3 + 2) * Nn + nw + 2 * tn + nn];
        }

        // ---- partial logit over own 32 channels (qk: LDS b128, 2-way free) ----
        const float* qrow = qk_lds + (w * 16 + 2 * t + nn) * 68 + 32 * h;
        float l0 = 0.f, l1 = 0.f, l2 = 0.f, l3 = 0.f;
#pragma unroll
        for (int j = 0; j < 8; ++j) {
            const float4 qv = ((const float4*)qrow)[j];
            l0 = fmaf(qv.x, npv[4 * j + 0], l0);
            l1 = fmaf(qv.y, npv[4 * j + 1], l1);
            l2 = fmaf(qv.z, npv[4 * j + 2], l2);
            l3 = fmaf(qv.w, npv[4 * j + 3], l3);
        }
        float lp = (l0 + l1) + (l2 + l3);
        if (h) lp += pp.x * d0 + pp.y * d1 + pp.z * d2 + pp.w * dn;
        // (bp term constant in s -> cancels in softmax)

        // cross-half combine: ONE in-wave shuffle, no barrier
        const float logit = lp + __shfl_xor(lp, 32);

        // ---- softmax over s (pure DPP in rows of 16) ----
        const float mx = rmax16(logit);
        const float e = __expf(logit - mx);
        const float se = rsum16(e);
        const float attn = e / se;

        // ---- fused vbar + Wv matvec over own 32 channels;
        //      npv[c] refilled in place right after its last use ----
        const float* npb_n = npb0 + (size_t)(((t + 1 < ITERS) ? t + 1 : t)) * 32;
        float4 oa = make_float4(0.f, 0.f, 0.f, 0.f);
#pragma unroll
        for (int c = 0; c < 32; ++c) {
            const float r = rsum16(attn * npv[c]);              // vbar[32h+c, nn]
            const float4 wq = *(const float4*)&wvT[(32 * h + c) * 68 + 4 * s];
            oa.x = fmaf(r, wq.x, oa.x);
            oa.y = fmaf(r, wq.y, oa.y);
            oa.z = fmaf(r, wq.z, oa.z);
            oa.w = fmaf(r, wq.w, oa.w);
            npv[c] = npb_n[(size_t)c * NS];                     // liveness refill
        }
        if (h) {    // tail channels 64..66 (= tmp d0,d1,d2)
            const float t0 = rsum16(attn * d0);
            const float t1 = rsum16(attn * d1);
            const float t2 = rsum16(attn * d2);
            const float4 wA = *(const float4*)&wvT[64 * 68 + 4 * s];
            const float4 wB = *(const float4*)&wvT[65 * 68 + 4 * s];
            const float4 wC = *(const float4*)&wvT[66 * 68 + 4 * s];
            oa.x += t0 * wA.x + t1 * wB.x + t2 * wC.x;
            oa.y += t0 * wA.y + t1 * wB.y + t2 * wC.y;
            oa.z += t0 * wA.z + t1 * wB.z + t2 * wC.z;
            oa.w += t0 * wA.w + t1 * wB.w + t2 * wC.w;
        }

        // cross-half output combine: 4 in-wave shuffles, no barrier
        oa.x += __shfl_xor(oa.x, 32);
        oa.y += __shfl_xor(oa.y, 32);
        oa.z += __shfl_xor(oa.z, 32);
        oa.w += __shfl_xor(oa.w, 32);

        if (!h) {   // h=0 lanes store: out[o = 4s+j][ng+nn]
            float* ob = out + ((size_t)(b * 64 + 4 * s)) * Nn + ng + nn;
            ob[0]              = oa.x;
            ob[(size_t)Nn]     = oa.y;
            ob[(size_t)Nn * 2] = oa.z;
            ob[(size_t)Nn * 3] = oa.w;
        }
    }
}

extern "C" void kernel_launch(void* const* d_in, const int* in_sizes, int n_in,
                              void* d_out, int out_size, void* d_ws, size_t ws_size,
                              hipStream_t stream) {
    const float* xyz    = (const float*)d_in[0];
    const float* nxyz   = (const float*)d_in[1];
    const float* points = (const float*)d_in[2];
    const float* npts   = (const float*)d_in[3];
    const float* Wk     = (const float*)d_in[4];
    const float* Wv     = (const float*)d_in[5];
    const float* Wp     = (const float*)d_in[6];
    // d_in[7] = bp — unused: constant-in-s logit shift cancels in softmax
    float* out = (float*)d_out;

    hipLaunchKernelGGL(attn_fused_kernel, dim3(1024), dim3(256), 0, stream,
                       xyz, nxyz, points, npts, Wk, Wv, Wp, out);
}

// Round 17
// 150.662 us; speedup vs baseline: 2.5141x; 1.9393x over previous
//
#include <hip/hip_runtime.h>
#include <math.h>

constexpr int Nn = 16384;
constexpr size_t NS = (size_t)Nn * 16;      // dwords per channel plane of npts

// ---- DPP helpers (rows of 16, pure VALU) ----
template <int CTRL>
__device__ __forceinline__ float dpp_f(float x) {
    return __int_as_float(
        __builtin_amdgcn_update_dpp(0, __float_as_int(x), CTRL, 0xF, 0xF, false));
}
__device__ __forceinline__ float rsum16(float v) {
    v += dpp_f<0x128>(v); v += dpp_f<0x124>(v);
    v += dpp_f<0x122>(v); v += dpp_f<0x121>(v);
    return v;
}
__device__ __forceinline__ float rmax16(float v) {
    v = fmaxf(v, dpp_f<0x128>(v)); v = fmaxf(v, dpp_f<0x124>(v));
    v = fmaxf(v, dpp_f<0x122>(v)); v = fmaxf(v, dpp_f<0x121>(v));
    return v;
}

// bf16 pack/unpack (RNE round; exact <<16 expand)
__device__ __forceinline__ unsigned bf16_rne(unsigned u) {
    return (u + 0x7FFFu + ((u >> 16) & 1u)) >> 16;
}
__device__ __forceinline__ float blo(unsigned u) { return __uint_as_float(u << 16); }
__device__ __forceinline__ float bhi(unsigned u) { return __uint_as_float(u & 0xFFFF0000u); }

// ================= Kernel A: qk = Wk^T (q*scale), pp = Wp^T qk =================
// thread = (point, 16-channel quarter); no LDS. (unchanged, proven)
__global__ __launch_bounds__(256, 4) void qkpp_kernel(
    const float* __restrict__ points, const float* __restrict__ Wk,
    const float* __restrict__ Wp, float* __restrict__ ws)
{
    const int tid = threadIdx.x;
    const int lane = tid & 63;
    const int q = lane >> 4;                            // quarter 0..3
    const int pt = blockIdx.x * 64 + (tid >> 6) * 16 + (lane & 15);
    const int b = pt >> 14;
    const int n = pt & (Nn - 1);

    float qk[16];
#pragma unroll
    for (int k = 0; k < 16; ++k) qk[k] = 0.f;

    const float* prow = points + (size_t)b * 64 * Nn + n;
    const float* wkq = Wk + 16 * q;
#pragma unroll 4
    for (int c = 0; c < 64; ++c) {
        const float qv = prow[(size_t)c * Nn];
        const float4 w0 = *(const float4*)(wkq + c * 64 + 0);
        const float4 w1 = *(const float4*)(wkq + c * 64 + 4);
        const float4 w2 = *(const float4*)(wkq + c * 64 + 8);
        const float4 w3 = *(const float4*)(wkq + c * 64 + 12);
        qk[0]  = fmaf(qv, w0.x, qk[0]);  qk[1]  = fmaf(qv, w0.y, qk[1]);
        qk[2]  = fmaf(qv, w0.z, qk[2]);  qk[3]  = fmaf(qv, w0.w, qk[3]);
        qk[4]  = fmaf(qv, w1.x, qk[4]);  qk[5]  = fmaf(qv, w1.y, qk[5]);
        qk[6]  = fmaf(qv, w1.z, qk[6]);  qk[7]  = fmaf(qv, w1.w, qk[7]);
        qk[8]  = fmaf(qv, w2.x, qk[8]);  qk[9]  = fmaf(qv, w2.y, qk[9]);
        qk[10] = fmaf(qv, w2.z, qk[10]); qk[11] = fmaf(qv, w2.w, qk[11]);
        qk[12] = fmaf(qv, w3.x, qk[12]); qk[13] = fmaf(qv, w3.y, qk[13]);
        qk[14] = fmaf(qv, w3.z, qk[14]); qk[15] = fmaf(qv, w3.w, qk[15]);
    }
#pragma unroll
    for (int k = 0; k < 16; ++k) qk[k] *= 0.125f;       // fold SCALE

    float p0 = 0.f, p1 = 0.f, p2 = 0.f, p3 = 0.f;
#pragma unroll
    for (int k = 0; k < 16; ++k) {
        const float4 wp4 = *(const float4*)(Wp + (16 * q + k) * 4);
        p0 = fmaf(qk[k], wp4.x, p0);
        p1 = fmaf(qk[k], wp4.y, p1);
        p2 = fmaf(qk[k], wp4.z, p2);
        p3 = fmaf(qk[k], wp4.w, p3);
    }
    p0 += __shfl_xor(p0, 16); p0 += __shfl_xor(p0, 32);
    p1 += __shfl_xor(p1, 16); p1 += __shfl_xor(p1, 32);
    p2 += __shfl_xor(p2, 16); p2 += __shfl_xor(p2, 32);
    p3 += __shfl_xor(p3, 16); p3 += __shfl_xor(p3, 32);

    float* orow = ws + (size_t)pt * 68 + 16 * q;
    ((float4*)orow)[0] = make_float4(qk[0],  qk[1],  qk[2],  qk[3]);
    ((float4*)orow)[1] = make_float4(qk[4],  qk[5],  qk[6],  qk[7]);
    ((float4*)orow)[2] = make_float4(qk[8],  qk[9],  qk[10], qk[11]);
    ((float4*)orow)[3] = make_float4(qk[12], qk[13], qk[14], qk[15]);
    if (q == 0)
        *(float4*)(ws + (size_t)pt * 68 + 64) = make_float4(p0, p1, p2, p3);
}

// ====== Kernel B: LDS-staged streamer (global_load_lds; zero reg-resident np) ======
// Block = 16 consecutive points, one-shot. np tile (64ch x 16pt x 16s = 64KB)
// DMA'd into LDS with zero VGPR cost; Wv packed bf16 (9.2KB) so total LDS
// 77.3KB -> 2 blocks/CU (one stages while the other computes).
// Thread = (p = t>>4, s = t&15). One barrier total.
__global__ __launch_bounds__(256, 2) void attn_stream_kernel(
    const float* __restrict__ xyz, const float* __restrict__ nxyz,
    const float* __restrict__ npts, const float* __restrict__ Wv,
    const float* __restrict__ ws, float* __restrict__ out)
{
    __shared__ float np_lds[64 * 256];                 // [c][p*16+s], linear (DMA layout)
    __shared__ __align__(16) float qk_lds[16 * 68];    // [p][64 qk + 4 pp]
    __shared__ __align__(16) unsigned wvP[34 * 68];    // [cp][o]: bf16 pair (c=2cp, 2cp+1)

    const int t = threadIdx.x;
    const int w = t >> 6;
    const int l = t & 63;
    const int s = t & 15;
    const int p = t >> 4;                              // 0..15
    const int gpt = blockIdx.x * 16;                   // 16-pt chunk, never straddles b
    const int b = gpt >> 14;
    const int n0 = gpt & (Nn - 1);

    // ---- 1) async np tile stage: wave w DMAs planes c = 16w..16w+15 ----
    // src: plane c at column n0*16, lane covers 16B -> 1KB/instr contiguous.
    // LDS dest: wave-uniform base + lane*16 (HW layout) == np_lds[c][0..255].
    {
        const float* src0 = npts + (size_t)(b * 64 + 16 * w) * NS + (size_t)n0 * 16 + 4 * l;
        float* dst0 = np_lds + (16 * w) * 256;
#pragma unroll
        for (int k = 0; k < 16; ++k) {
            __builtin_amdgcn_global_load_lds(src0 + (size_t)k * NS, dst0 + k * 256, 16, 0, 0);
        }
    }

    // ---- 2) qk/pp stage from ws (contiguous 1088 dwords) ----
    for (int i = t; i < 16 * 68; i += 256)
        qk_lds[i] = ws[(size_t)gpt * 68 + i];

    // ---- 3) Wv -> bf16-packed wvP[cp][o] ----
    for (int i = t; i < 64 * 34; i += 256) {
        const int o = i / 34, cp = i - o * 34;
        const int c0 = 2 * cp;
        const unsigned ulo = __float_as_uint(Wv[o * 67 + c0]);
        const unsigned uhi = (c0 + 1 < 67) ? __float_as_uint(Wv[o * 67 + c0 + 1]) : 0u;
        wvP[cp * 68 + o] = bf16_rne(ulo) | (bf16_rne(uhi) << 16);
    }

    // ---- 4) relative position per thread (p, s) ----
    const float nx0 = nxyz[((size_t)(b * 3 + 0) * Nn + n0) * 16 + t];
    const float nx1 = nxyz[((size_t)(b * 3 + 1) * Nn + n0) * 16 + t];
    const float nx2 = nxyz[((size_t)(b * 3 + 2) * Nn + n0) * 16 + t];
    const float x0 = xyz[(size_t)(b * 3 + 0) * Nn + n0 + p];
    const float x1 = xyz[(size_t)(b * 3 + 1) * Nn + n0 + p];
    const float x2 = xyz[(size_t)(b * 3 + 2) * Nn + n0 + p];
    const float d0 = x0 - nx0, d1 = x1 - nx1, d2 = x2 - nx2;
    const float dn = sqrtf(d0 * d0 + d1 * d1 + d2 * d2);

    __syncthreads();   // drains vmcnt (np DMA + staging loads) + lgkm -> tile ready

    // ---- 5) pass 1: logit = qk . np + pp . pos ----
    const float* qrow = qk_lds + p * 68;
    float l0 = 0.f, l1 = 0.f, l2 = 0.f, l3 = 0.f;
#pragma unroll
    for (int c4 = 0; c4 < 16; ++c4) {
        const float4 qq = ((const float4*)qrow)[c4];   // b128, 16 distinct (broadcast)
        l0 = fmaf(qq.x, np_lds[(4 * c4 + 0) * 256 + t], l0);   // consecutive dwords
        l1 = fmaf(qq.y, np_lds[(4 * c4 + 1) * 256 + t], l1);
        l2 = fmaf(qq.z, np_lds[(4 * c4 + 2) * 256 + t], l2);
        l3 = fmaf(qq.w, np_lds[(4 * c4 + 3) * 256 + t], l3);
    }
    const float4 pp = ((const float4*)qrow)[16];
    float logit = (l0 + l1) + (l2 + l3);
    logit += pp.x * d0 + pp.y * d1 + pp.z * d2 + pp.w * dn;
    // (bp term constant in s -> cancels in softmax)

    // ---- 6) softmax over s (DPP rows of 16; row = fixed p) ----
    const float mx = rmax16(logit);
    const float e = __expf(logit - mx);
    const float se = rsum16(e);
    const float attn = e / se;

    // ---- 7) pass 2: fused vbar + bf16-Wv matvec; lane (p,s) owns o = 4s..4s+3 ----
    float4 oa = make_float4(0.f, 0.f, 0.f, 0.f);
#pragma unroll
    for (int cp = 0; cp < 32; ++cp) {
        const float n0v = np_lds[(2 * cp + 0) * 256 + t];
        const float n1v = np_lds[(2 * cp + 1) * 256 + t];
        const float r0 = rsum16(attn * n0v);           // vbar[2cp  ][p] in all row lanes
        const float r1 = rsum16(attn * n1v);           // vbar[2cp+1][p]
        const uint4 wq = *(const uint4*)&wvP[cp * 68 + 4 * s];   // 8 bf16 weights
        oa.x = fmaf(r0, blo(wq.x), oa.x); oa.x = fmaf(r1, bhi(wq.x), oa.x);
        oa.y = fmaf(r0, blo(wq.y), oa.y); oa.y = fmaf(r1, bhi(wq.y), oa.y);
        oa.z = fmaf(r0, blo(wq.z), oa.z); oa.z = fmaf(r1, bhi(wq.z), oa.z);
        oa.w = fmaf(r0, blo(wq.w), oa.w); oa.w = fmaf(r1, bhi(wq.w), oa.w);
    }
    {   // tail channels 64..66 (= tmp d0,d1,d2); packed at cp=32 (64,65), cp=33 (66,0)
        const float t0 = rsum16(attn * d0);
        const float t1 = rsum16(attn * d1);
        const float t2 = rsum16(attn * d2);
        const uint4 wqa = *(const uint4*)&wvP[32 * 68 + 4 * s];
        const uint4 wqb = *(const uint4*)&wvP[33 * 68 + 4 * s];
        oa.x += t0 * blo(wqa.x) + t1 * bhi(wqa.x) + t2 * blo(wqb.x);
        oa.y += t0 * blo(wqa.y) + t1 * bhi(wqa.y) + t2 * blo(wqb.y);
        oa.z += t0 * blo(wqa.z) + t1 * bhi(wqa.z) + t2 * blo(wqb.z);
        oa.w += t0 * blo(wqa.w) + t1 * bhi(wqa.w) + t2 * blo(wqb.w);
    }

    // ---- 8) stores: out[o = 4s+j][n0+p] ----
    float* ob = out + ((size_t)(b * 64 + 4 * s)) * Nn + n0 + p;
    ob[0]              = oa.x;
    ob[(size_t)Nn]     = oa.y;
    ob[(size_t)Nn * 2] = oa.z;
    ob[(size_t)Nn * 3] = oa.w;
}

extern "C" void kernel_launch(void* const* d_in, const int* in_sizes, int n_in,
                              void* d_out, int out_size, void* d_ws, size_t ws_size,
                              hipStream_t stream) {
    const float* xyz    = (const float*)d_in[0];
    const float* nxyz   = (const float*)d_in[1];
    const float* points = (const float*)d_in[2];
    const float* npts   = (const float*)d_in[3];
    const float* Wk     = (const float*)d_in[4];
    const float* Wv     = (const float*)d_in[5];
    const float* Wp     = (const float*)d_in[6];
    // d_in[7] = bp — unused: constant-in-s logit shift cancels in softmax
    float* out = (float*)d_out;
    float* ws = (float*)d_ws;   // [65536][68] fp32 = 17.8 MB, fully rewritten each call

    hipLaunchKernelGGL(qkpp_kernel,        dim3(1024), dim3(256), 0, stream,
                       points, Wk, Wp, ws);
    hipLaunchKernelGGL(attn_stream_kernel, dim3(4096), dim3(256), 0, stream,
                       xyz, nxyz, npts, Wv, ws, out);
}